// Round 4
// baseline (314.281 us; speedup 1.0000x reference)
//
#include <hip/hip_runtime.h>

// Problem constants
#define NB 16
#define CC 512
#define WW 4096
#define NMASK 1024          // NUM_MASKS * MASK_WIDTH
#define T_COMB 11264        // 1024 masked + 10240 negative rows
#define OUT0_ELEMS (NB*CC*WW)   // 33554432 floats

// Workspace layout (bytes):
//   [0, 256KB)           : int32 lookup[N*W]  (flat pos -> combined row g, or -1)
//   [256KB, 768KB)       : bf16 Wq  [512][512]
//   [768KB, ~12.3MB)     : bf16 A   [11264][512]
#define WS_LOOKUP_OFF 0
#define WS_WQ_OFF     262144
#define WS_A_OFF      786432

#define S_LDS 36            // ushort stride per c-row in the transpose tile

typedef __attribute__((ext_vector_type(8))) short short8;
typedef __attribute__((ext_vector_type(4))) float f32x4;

__device__ __forceinline__ unsigned short f2bf(float x) {
  unsigned int u = __builtin_bit_cast(unsigned int, x);
  u += 0x7fffu + ((u >> 16) & 1u);   // round-to-nearest-even
  return (unsigned short)(u >> 16);
}

__device__ __forceinline__ void gload_lds16(const void* gp, void* lp) {
  __builtin_amdgcn_global_load_lds(
      (__attribute__((address_space(1))) void*)(gp),
      (__attribute__((address_space(3))) void*)(lp),
      16, 0, 0);
}

// K0b: blocks 0..43 scatter combined row ids into the (memset to -1) lookup;
// blocks 44..107 convert Wq fp32 -> bf16.
__global__ __launch_bounds__(256) void prep_k(
    const int* __restrict__ pack_idx, const int* __restrict__ masked_idx,
    const int* __restrict__ neg_idx, int* __restrict__ lookup,
    const float* __restrict__ Wq, unsigned short* __restrict__ Wq_ws) {
  int b = blockIdx.x;
  if (b < 44) {
    int g = b * 256 + (int)threadIdx.x;        // 44*256 == 11264 exactly
    int pidx = (g < NMASK) ? masked_idx[g] : neg_idx[g - NMASK];
    lookup[pack_idx[pidx]] = g;
  } else {
    int b2 = b - 44;
    const float4* wq4 = (const float4*)Wq;
#pragma unroll
    for (int it = 0; it < 4; ++it) {
      int i4 = it * 16384 + b2 * 256 + (int)threadIdx.x;
      float4 v = wq4[i4];
      ushort4 o;
      o.x = f2bf(v.x); o.y = f2bf(v.y); o.z = f2bf(v.z); o.w = f2bf(v.w);
      ((ushort4*)Wq_ws)[i4] = o;
    }
  }
}

// K1: tile-transpose streaming copy. Block = (n, all c, 32 w), processed in
// two 256-c halves so the LDS tile is 18 KB -> 8 blocks/CU occupancy.
// seq_len is a multiple of 128 -> every 32-w tile is all-valid or all-invalid.
__global__ __launch_bounds__(256) void fused_copy_k(
    const float* __restrict__ in, const int* __restrict__ seq_len,
    const int* __restrict__ lookup, const float* __restrict__ mask_emb,
    float* __restrict__ out0, unsigned short* __restrict__ A_ws) {
  const int tid = threadIdx.x;
  const int bx = blockIdx.x;
  const int n = bx >> 7;                 // 16 n-lines
  const int w0 = (bx & 127) * 32;        // 128 w-tiles per line
  const int wl4 = (tid & 7) * 4;         // this thread's 4-w slot
  const int w = w0 + wl4;
  const int c0 = tid >> 3;               // 0..31
  const size_t rowbase = ((size_t)n << 21) + (size_t)w;   // element index
  float4* out4 = (float4*)out0;
  const int L = seq_len[n];

  if (w0 + 32 > L) {
    // fully-invalid tile: zero-fill out0, nothing else to do
    float4 z = {0.f, 0.f, 0.f, 0.f};
#pragma unroll
    for (int it = 0; it < 16; ++it) {
      int c = it * 32 + c0;
      out4[(rowbase + ((size_t)c << 12)) >> 2] = z;
    }
    return;
  }

  __shared__ unsigned short tile[256 * S_LDS];   // 18 KB
  __shared__ int g_s[32];
  if (tid < 32) g_s[tid] = lookup[n * WW + w0 + tid];

  const int4 g4 = *(const int4*)&lookup[n * WW + w];   // 16B aligned
  const int gg[4] = {g4.x, g4.y, g4.z, g4.w};
  bool lane_has_mask = ((unsigned)gg[0] < (unsigned)NMASK) |
                       ((unsigned)gg[1] < (unsigned)NMASK) |
                       ((unsigned)gg[2] < (unsigned)NMASK) |
                       ((unsigned)gg[3] < (unsigned)NMASK);
  // every wave contains all 8 w4-groups -> ballot is block-wide truth
  bool has_mask = __ballot(lane_has_mask) != 0ull;

  const float4* in4 = (const float4*)in;
  unsigned smask = 0;
#pragma unroll
  for (int half = 0; half < 2; ++half) {
    const int cbase = half << 8;
#pragma unroll
    for (int it = 0; it < 8; ++it) {
      int c = cbase + it * 32 + c0;
      size_t i4 = (rowbase + ((size_t)c << 12)) >> 2;
      float4 v = in4[i4];
      ushort4 bf;
      bf.x = f2bf(v.x); bf.y = f2bf(v.y); bf.z = f2bf(v.z); bf.w = f2bf(v.w);
      *(ushort4*)&tile[(c - cbase) * S_LDS + wl4] = bf;
      if (has_mask) {   // wave-uniform branch
        float o[4] = {v.x, v.y, v.z, v.w};
#pragma unroll
        for (int k = 0; k < 4; ++k)
          if ((unsigned)gg[k] < (unsigned)NMASK)
            o[k] = mask_emb[(gg[k] & 3) * CC + c];
        v.x = o[0]; v.y = o[1]; v.z = o[2]; v.w = o[3];
      }
      out4[i4] = v;
    }
    __syncthreads();
    if (half == 0) {
      const int lane = tid & 63;
      bool sel = (lane < 32) && (g_s[lane] >= 0);
      smask = (unsigned)__ballot(sel);
    }
    // Phase 2: coalesced half-row emission (512 B per selected slot)
    unsigned m = smask;
    while (m) {
      int wl = __builtin_ctz(m);
      m &= m - 1;
      int g = g_s[wl];
      A_ws[(size_t)g * CC + cbase + tid] = tile[tid * S_LDS + wl];
    }
    if (half == 0) __syncthreads();   // protect tile before half-1 overwrite
  }
}

// K2: bf16 MFMA GEMM  out[m,f] = sum_c A[m,c]*Wq[f,c] + bq[f]
// M=11264, N=512, K=512.  64x64 block tile -> 1408 blocks (5.5/CU, even
// makespan), 8 KB LDS, 8 blocks/CU to hide the per-iter staging drain.
__global__ __launch_bounds__(256, 8) void gemm_k(
    const unsigned short* __restrict__ A, const unsigned short* __restrict__ B,
    const float* __restrict__ bq, float* __restrict__ out) {
  __shared__ unsigned short As[64 * 32];    // 4 KB
  __shared__ unsigned short Bs[64 * 32];    // 4 KB
  const int tid = threadIdx.x;
  const int lane = tid & 63;
  const int quad = lane >> 4;
  const int r16 = lane & 15;
  const int wv = tid >> 6;
  const int bm = blockIdx.x * 64;
  const int bf = blockIdx.y * 64;
  const int wm = (wv & 1) * 32;
  const int wf = (wv >> 1) * 32;
  const int wbase = tid & ~63;   // wave-uniform
  const int row = tid >> 2, cg = tid & 3;

  f32x4 acc[2][2];
#pragma unroll
  for (int mi = 0; mi < 2; ++mi)
#pragma unroll
    for (int fi = 0; fi < 2; ++fi)
      acc[mi][fi] = (f32x4){0.f, 0.f, 0.f, 0.f};

  for (int k0 = 0; k0 < 512; k0 += 32) {
    // Stage 64x32 bf16 tiles: 256 16B-chunks each, one pass per operand.
    gload_lds16(A + (size_t)(bm + row) * 512 + k0 + cg * 8, &As[wbase * 8]);
    gload_lds16(B + (size_t)(bf + row) * 512 + k0 + cg * 8, &Bs[wbase * 8]);
    asm volatile("s_waitcnt vmcnt(0)" ::: "memory");
    __syncthreads();

    short8 a[2], b[2];
#pragma unroll
    for (int mi = 0; mi < 2; ++mi)
      a[mi] = *(const short8*)&As[(wm + mi * 16 + r16) * 32 + quad * 8];
#pragma unroll
    for (int fi = 0; fi < 2; ++fi)
      b[fi] = *(const short8*)&Bs[(wf + fi * 16 + r16) * 32 + quad * 8];
#pragma unroll
    for (int mi = 0; mi < 2; ++mi)
#pragma unroll
      for (int fi = 0; fi < 2; ++fi)
        acc[mi][fi] = __builtin_amdgcn_mfma_f32_16x16x32_bf16(
            a[mi], b[fi], acc[mi][fi], 0, 0, 0);
    __syncthreads();
  }

  // Epilogue: C/D layout col = lane&15 (f), row = quad*4 + reg (m).
#pragma unroll
  for (int fi = 0; fi < 2; ++fi) {
    int f = bf + wf + fi * 16 + r16;
    float bqv = bq[f];
#pragma unroll
    for (int mi = 0; mi < 2; ++mi) {
      int m0 = bm + wm + mi * 16 + quad * 4;
#pragma unroll
      for (int r = 0; r < 4; ++r)
        out[(size_t)(m0 + r) * 512 + f] = acc[mi][fi][r] + bqv;
    }
  }
}

extern "C" void kernel_launch(void* const* d_in, const int* in_sizes, int n_in,
                              void* d_out, int out_size, void* d_ws, size_t ws_size,
                              hipStream_t stream) {
  const float* inputs    = (const float*)d_in[0];
  const int*   seq_len   = (const int*)d_in[1];
  const int*   pack_idx  = (const int*)d_in[2];
  const int*   masked_idx= (const int*)d_in[3];
  const int*   neg_idx   = (const int*)d_in[4];
  const float* mask_emb  = (const float*)d_in[5];
  const float* Wq        = (const float*)d_in[6];
  const float* bq        = (const float*)d_in[7];
  float* out = (float*)d_out;
  char* ws = (char*)d_ws;
  int* lookup = (int*)(ws + WS_LOOKUP_OFF);
  unsigned short* wqb = (unsigned short*)(ws + WS_WQ_OFF);
  unsigned short* aws = (unsigned short*)(ws + WS_A_OFF);

  hipMemsetAsync(lookup, 0xFF, NB * WW * sizeof(int), stream);  // all -1
  prep_k<<<108, 256, 0, stream>>>(pack_idx, masked_idx, neg_idx, lookup, Wq, wqb);
  fused_copy_k<<<2048, 256, 0, stream>>>(inputs, seq_len, lookup, mask_emb,
                                         out, aws);
  gemm_k<<<dim3(176, 8), 256, 0, stream>>>(aws, wqb, bq, out + OUT0_ELEMS);
}